// Round 8
// baseline (218.962 us; speedup 1.0000x reference)
//
#include <hip/hip_runtime.h>
#include <hip/hip_bf16.h>
#include <math.h>

#define NF 26
#define VOCAB 100000
#define EMB 16
#define BATCH 16384
#define NTOT 416    // 26*16
#define NCHUNK 13   // 416 / 32 (MFMA K)
#define RPB 8       // real rows per wave (MFMA tile rows 8..15 duplicate 0..7)

typedef __attribute__((ext_vector_type(8))) short bf16x8;  // 8 bf16 (4 VGPRs)
typedef __attribute__((ext_vector_type(4))) float f32x4;   // MFMA C/D
typedef __attribute__((ext_vector_type(4))) float vf4;

__device__ __forceinline__ short2 cvt_pk(float a, float b) {
    union { __hip_bfloat162 h; short2 s; } u;
    u.h = __float22bfloat162_rn(make_float2(a, b));  // v_cvt_pk_bf16_f32
    return u.s;
}

__device__ __forceinline__ bf16x8 pack8(vf4 a, vf4 b) {
    short2 p0 = cvt_pk(a.x, a.y), p1 = cvt_pk(a.z, a.w);
    short2 p2 = cvt_pk(b.x, b.y), p3 = cvt_pk(b.z, b.w);
    bf16x8 r;
    r[0] = p0.x; r[1] = p0.y; r[2] = p1.x; r[3] = p1.y;
    r[4] = p2.x; r[5] = p2.y; r[6] = p3.x; r[7] = p3.y;
    return r;
}

// One wave/block; 8 batch rows via one 16x16 MFMA tile over 13 K=32 chunks.
// Gather: each 64 B (row,field) line covered by ONE instruction (13 VMEM
// gathers/wave, 208 unique line-touches). Cross-lane A-fragment exchange
// through LDS + __syncthreads (R6's shfl reassembly was flaky).
// R8 probe: gathers are CACHED (no nt) -- the harness's per-iteration table
// restore plausibly leaves tables Infinity-Cache-resident; NT was winning
// only under the old 2x request pressure (R5).
__global__ __launch_bounds__(64, 2) void fm_kernel(
    const int* __restrict__ X, const float* __restrict__ tables,
    const float* __restrict__ W, const float* __restrict__ bptr,
    const float* __restrict__ v, float* __restrict__ out) {
    __shared__ vf4 exA[NCHUNK][64];  // 13312 B: gather exchange buffer
    __shared__ float2 wvs[NTOT];     // 3328 B: {W[n], -0.5*sum_k v[n][k]^2}

    const int l = threadIdx.x;
    const int col = l & 15;        // A-row m (pair col/col+8) / B-col n
    const int quad = l >> 4;
    const int hi = (col >> 3) & 1; // which 16B segment of the 32B half
    const int hsel = quad & 1;     // which 32B half of the field row
    const int fpar = quad >> 1;    // field parity this lane covers
    const int r = blockIdx.x * RPB + (col & 7);

    // --- 13 independent idx loads (strided dwords share cache lines) ---
    int idxv[NCHUNK];
    {
        const int* xr = X + r * NF + fpar;
#pragma unroll
        for (int c = 0; c < NCHUNK; ++c) idxv[c] = xr[2 * c];
    }

    // --- 13 gathers, one 16B segment per lane, issued upfront (cached) ---
    vf4 gown[NCHUNK];
#pragma unroll
    for (int c = 0; c < NCHUNK; ++c) {
        const int f = 2 * c + fpar;
        const int seg = hsel * 2 + hi;  // 16B segment within the 64B row
        const char* base = (const char*)tables +
                           (((unsigned)(f * VOCAB + idxv[c])) << 6) +
                           (seg << 4);
        gown[c] = *(const vf4*)base;
    }

    // --- wv staging (overlaps gather latency): lin - 0.5*sos =
    //     sum_n e*(W[n] + e*u[n]), u = -0.5*sum_k v[n][k]^2 ---
    for (int n = l; n < NTOT; n += 64) {
        const float4* vr = (const float4*)(v + n * 16);
        float4 a0 = vr[0], a1 = vr[1], a2 = vr[2], a3 = vr[3];
        float s = a0.x * a0.x;
        s = fmaf(a0.y, a0.y, s); s = fmaf(a0.z, a0.z, s); s = fmaf(a0.w, a0.w, s);
        s = fmaf(a1.x, a1.x, s); s = fmaf(a1.y, a1.y, s); s = fmaf(a1.z, a1.z, s);
        s = fmaf(a1.w, a1.w, s); s = fmaf(a2.x, a2.x, s); s = fmaf(a2.y, a2.y, s);
        s = fmaf(a2.z, a2.z, s); s = fmaf(a2.w, a2.w, s); s = fmaf(a3.x, a3.x, s);
        s = fmaf(a3.y, a3.y, s); s = fmaf(a3.z, a3.z, s); s = fmaf(a3.w, a3.w, s);
        wvs[n] = make_float2(W[n], -0.5f * s);
    }

    // --- B fragments: whole v in wave registers (cached loads, reused) ---
    bf16x8 Bf[NCHUNK];
#pragma unroll
    for (int c = 0; c < NCHUNK; ++c) {
        const float* vp = v + (c * 32 + quad * 8) * 16 + col;
        vf4 b0 = {vp[0], vp[16], vp[32], vp[48]};
        vf4 b1 = {vp[64], vp[80], vp[96], vp[112]};
        Bf[c] = pack8(b0, b1);
    }

    // --- park gathers in LDS for the cross-lane fragment exchange ---
#pragma unroll
    for (int c = 0; c < NCHUNK; ++c) exA[c][l] = gown[c];

    __syncthreads();

    // --- main loop: fragment reads from LDS + t-partials + MFMA ---
    // Owner algebra: elements n = c*32 + quad*8 + {0..7} of row m live in
    // lanes quad*16 + (m&7) (first 4, hi=0) and +8 (last 4, hi=1).
    f32x4 acc = {0.f, 0.f, 0.f, 0.f};
    float tp = 0.f;
    const int ebase = quad * 16 + (col & 7);
#pragma unroll
    for (int c = 0; c < NCHUNK; ++c) {
        vf4 e0 = exA[c][ebase];
        vf4 e1 = exA[c][ebase + 8];

        const float4* wp = (const float4*)&wvs[c * 32 + quad * 8];
        float4 w0 = wp[0], w1 = wp[1], w2 = wp[2], w3 = wp[3];
        tp = fmaf(e0.x, fmaf(e0.x, w0.y, w0.x), tp);
        tp = fmaf(e0.y, fmaf(e0.y, w0.w, w0.z), tp);
        tp = fmaf(e0.z, fmaf(e0.z, w1.y, w1.x), tp);
        tp = fmaf(e0.w, fmaf(e0.w, w1.w, w1.z), tp);
        tp = fmaf(e1.x, fmaf(e1.x, w2.y, w2.x), tp);
        tp = fmaf(e1.y, fmaf(e1.y, w2.w, w2.z), tp);
        tp = fmaf(e1.z, fmaf(e1.z, w3.y, w3.x), tp);
        tp = fmaf(e1.w, fmaf(e1.w, w3.w, w3.z), tp);
        acc = __builtin_amdgcn_mfma_f32_16x16x32_bf16(pack8(e0, e1), Bf[c],
                                                      acc, 0, 0, 0);
    }

    // --- reduce t = lin - 0.5*sos over the 4 quads ---
    tp += __shfl_xor(tp, 16);
    tp += __shfl_xor(tp, 32);

    // --- S[row] = sum_k xv^2 : butterfly over the 16 n-lanes (C-layout) ---
    float s0 = acc[0] * acc[0], s1 = acc[1] * acc[1];
    float s2 = acc[2] * acc[2], s3 = acc[3] * acc[3];
#pragma unroll
    for (int mask = 1; mask < 16; mask <<= 1) {
        s0 += __shfl_xor(s0, mask);
        s1 += __shfl_xor(s1, mask);
        s2 += __shfl_xor(s2, mask);
        s3 += __shfl_xor(s3, mask);
    }

    // --- route t to the S holders: row quad*4+reg lives in lane quad*4+reg
    float t0 = __shfl(tp, quad * 4 + 0);
    float t1 = __shfl(tp, quad * 4 + 1);
    float t2 = __shfl(tp, quad * 4 + 2);
    float t3 = __shfl(tp, quad * 4 + 3);

    if (col == 0 && quad < 2) {  // rows 0..7 (quads 2,3 are duplicates)
        const float bb = bptr[0];
        float4 o;
        o.x = 1.f / (1.f + __expf(-(t0 + 0.5f * s0 + bb)));
        o.y = 1.f / (1.f + __expf(-(t1 + 0.5f * s1 + bb)));
        o.z = 1.f / (1.f + __expf(-(t2 + 0.5f * s2 + bb)));
        o.w = 1.f / (1.f + __expf(-(t3 + 0.5f * s3 + bb)));
        *(float4*)(out + blockIdx.x * RPB + quad * 4) = o;
    }
}

// Inputs: X[int32 16384x26], tables[f32 26x100000x16], W[f32 416x1],
// b[f32 1], v[f32 416x16]. Output: f32 [16384].
extern "C" void kernel_launch(void* const* d_in, const int* in_sizes, int n_in,
                              void* d_out, int out_size, void* d_ws,
                              size_t ws_size, hipStream_t stream) {
    const int* X = (const int*)d_in[0];
    const float* tables = (const float*)d_in[1];
    const float* W = (const float*)d_in[2];
    const float* b = (const float*)d_in[3];
    const float* v = (const float*)d_in[4];
    float* out = (float*)d_out;

    // 2048 single-wave blocks = 8 blocks/CU, fully co-resident.
    fm_kernel<<<BATCH / RPB, 64, 0, stream>>>(X, tables, W, b, v, out);
}